// Round 7
// baseline (202.335 us; speedup 1.0000x reference)
//
#include <hip/hip_runtime.h>
#include <hip/hip_bf16.h>

#define C_DIM 100000
#define NROW 512
#define DDIM 512
#define BN 64
#define NPANEL 1563            // ceil(C_DIM/64); last panel has 32 valid cols
#define PANEL_ELEMS 32768      // 64 cols x 512 k bf16 = 64KB image
#define NSG 391                // ceil(NPANEL/4) stripe-groups of 256 cols

typedef __attribute__((ext_vector_type(4))) float f32x4;
typedef __attribute__((ext_vector_type(8))) short bf16x8;
typedef __attribute__((ext_vector_type(4))) float f32acc;

// ---- kernel A: fused norm-partials + transpose/convert W -> swizzled panels ----
// Block = (k-slab kb of 32 k) x (stripe sg of 256 c). Reads contiguous 1KB/wave
// segments, LDS-transposes, emits the EXACT LDS image kgemm4 will linear-copy:
//   img[c*512 + (q^(c&7))*8 + j] = bf16(W[q*8+j][cb+c]),  q=k>>3, j=k&7
__global__ __launch_bounds__(512) void cf_kprep(const float* __restrict__ W,
                                                float* __restrict__ norm2,
                                                __hip_bfloat16* __restrict__ Wt) {
    __shared__ __attribute__((aligned(16))) float X[32][264];
    const int tid = threadIdx.x;
    const int kb  = blockIdx.x & 15;
    const int sg  = blockIdx.x >> 4;
    const int c0g = sg * 256;

    #pragma unroll
    for (int it = 0; it < 4; ++it) {
        const int id = it * 512 + tid;
        const int kl = id >> 6;
        const int c4 = id & 63;
        const int cg = c0g + c4 * 4;
        f32x4 v = (f32x4){0.f, 0.f, 0.f, 0.f};
        if (cg + 3 < C_DIM) {
            v = *(const f32x4*)(W + (size_t)(kb * 32 + kl) * C_DIM + cg);
        } else {
            #pragma unroll
            for (int e = 0; e < 4; ++e)
                if (cg + e < C_DIM) v[e] = W[(size_t)(kb * 32 + kl) * C_DIM + cg + e];
        }
        *(f32x4*)&X[kl][c4 * 4] = v;
    }
    __syncthreads();

    // per-k sum of squares over this stripe
    {
        const int r = tid >> 4, seg = tid & 15;
        float s = 0.f;
        #pragma unroll
        for (int i = 0; i < 16; ++i) { float v = X[r][seg * 16 + i]; s += v * v; }
        #pragma unroll
        for (int off = 8; off; off >>= 1) s += __shfl_xor(s, off, 64);
        if (seg == 0) atomicAdd(&norm2[kb * 32 + r], s);
    }

    // emit: thread -> (piece = (panel pp, col c), half h); 2x16B contiguous stores
    const int pid = tid >> 1, h = tid & 1;
    const int pp  = pid >> 6, c = pid & 63;
    const int cl  = pp * 64 + c;
    const int panel = sg * 4 + pp;
    const int Qb  = (kb * 4) ^ (c & 4);
    __hip_bfloat16* dst = Wt + (size_t)panel * PANEL_ELEMS + c * 512 + Qb * 8;
    #pragma unroll
    for (int uu = 0; uu < 2; ++uu) {
        const int u = 2 * h + uu;
        const int t = u ^ (c & 3);            // k-octet within slab
        union { __hip_bfloat16 b[8]; bf16x8 v; } pk;
        #pragma unroll
        for (int j = 0; j < 8; ++j) pk.b[j] = __float2bfloat16(X[t * 8 + j][cl]);
        *(bf16x8*)(dst + u * 8) = pk.v;
    }
}

// ---------------- fallback kernel: norm2 (plain write) --------------------------
__global__ __launch_bounds__(256) void cf_knorm(const float* __restrict__ W,
                                                float* __restrict__ norm2) {
    const int d = blockIdx.x;
    const float* row = W + (size_t)d * C_DIM;
    float s = 0.f;
    for (int c4 = threadIdx.x; c4 < C_DIM / 4; c4 += 256) {
        f32x4 v = *(const f32x4*)(row + c4 * 4);
        s += v.x * v.x + v.y * v.y + v.z * v.z + v.w * v.w;
    }
    #pragma unroll
    for (int off = 32; off; off >>= 1) s += __shfl_down(s, off, 64);
    __shared__ float wsum[4];
    if ((threadIdx.x & 63) == 0) wsum[threadIdx.x >> 6] = s;
    __syncthreads();
    if (threadIdx.x == 0) norm2[d] = wsum[0] + wsum[1] + wsum[2] + wsum[3];
}

// ------- kernel 2: xs2 = bf16(x * rsqrt(norm2)) fragment-tiled ------------------
__global__ __launch_bounds__(256) void cf_kxs2(const float* __restrict__ x,
                                               const float* __restrict__ norm2,
                                               __hip_bfloat16* __restrict__ xs2) {
    const int idx = blockIdx.x * 256 + threadIdx.x;
    const int row = idx >> 6;
    const int k8  = idx & 63;
    const float* xp = x + (size_t)row * DDIM + k8 * 8;
    f32x4 v0 = *(const f32x4*)(xp);
    f32x4 v1 = *(const f32x4*)(xp + 4);
    union { __hip_bfloat16 h[8]; bf16x8 v; } p;
    #pragma unroll
    for (int e = 0; e < 4; ++e) p.h[e]     = __float2bfloat16(v0[e] * rsqrtf(norm2[k8 * 8 + e]));
    #pragma unroll
    for (int e = 0; e < 4; ++e) p.h[4 + e] = __float2bfloat16(v1[e] * rsqrtf(norm2[k8 * 8 + 4 + e]));
    *(bf16x8*)(xs2 + ((size_t)((row >> 4) * 64 + k8) * 128 + (row & 15) * 8)) = p.v;
}

// ---------------- kernel 3: target logits, cos_m, final -------------------------
__global__ __launch_bounds__(64) void cf_ktgt(const float* __restrict__ x,
                                              const float* __restrict__ W,
                                              const float* __restrict__ norm2,
                                              const int* __restrict__ label,
                                              float* __restrict__ tl,
                                              float* __restrict__ cm,
                                              float* __restrict__ fl) {
    const int i = blockIdx.x;
    const int lane = threadIdx.x;
    const int lab = label[i];
    float s = 0.f;
    for (int d = lane; d < DDIM; d += 64)
        s += x[(size_t)i * DDIM + d] * rsqrtf(norm2[d]) * W[(size_t)d * C_DIM + lab];
    #pragma unroll
    for (int off = 32; off; off >>= 1) s += __shfl_down(s, off, 64);
    if (lane == 0) {
        float t = fminf(fmaxf(s, -1.f), 1.f);
        float sn = sqrtf(fmaxf(1.f - t * t, 0.f));
        float c = t * 0.8775825618903728f - sn * 0.479425538604203f; // cos(th+m)
        tl[i] = t;
        cm[i] = c;
        fl[i] = (t > -0.8775825618903728f) ? c : (t - 0.2397127693021015f);
    }
}

// ---------------- kernel 4: t = 0.01 * mean(target_logit) -----------------------
__global__ __launch_bounds__(512) void cf_kt(const float* __restrict__ tl,
                                             float* __restrict__ tout) {
    float s = tl[threadIdx.x];
    #pragma unroll
    for (int off = 32; off; off >>= 1) s += __shfl_down(s, off, 64);
    __shared__ float w[8];
    if ((threadIdx.x & 63) == 0) w[threadIdx.x >> 6] = s;
    __syncthreads();
    if (threadIdx.x == 0) {
        float tt = 0.f;
        #pragma unroll
        for (int j = 0; j < 8; ++j) tt += w[j];
        tout[0] = 0.01f * (tt / 512.0f);
    }
}

// ------------- shared epilogue (D[c][i] acc -> curricular logits) ---------------
__device__ __forceinline__ void cf_epilogue(f32acc (&acc)[4][4], int wv, int il,
                                            int hi, int cb,
                                            const int* __restrict__ label,
                                            const float* __restrict__ cosm,
                                            const float* __restrict__ finl,
                                            float t, float* __restrict__ out) {
    const int ib = wv * 64;
    #pragma unroll
    for (int n = 0; n < 4; ++n) {
        const int i = ib + n * 16 + il;
        const float cmv = cosm[i];
        const float flv = finl[i];
        const int lab = label[i];
        float* orow = out + (size_t)i * C_DIM;
        #pragma unroll
        for (int m = 0; m < 4; ++m) {
            const int c0 = cb + m * 16 + hi * 4;
            if (c0 < C_DIM) {
                f32x4 v = acc[m][n];
                f32x4 o;
                #pragma unroll
                for (int r = 0; r < 4; ++r) {
                    float cz = fminf(fmaxf(v[r], -1.f), 1.f);
                    float ov = (cz > cmv) ? cz * (t + cz) : cz;
                    if (c0 + r == lab) ov = flv;
                    o[r] = ov * 64.0f;
                }
                *(f32x4*)(orow + c0) = o;
            }
        }
    }
}

// ------------- GEMM core (LDS image already staged) -----------------------------
__device__ __forceinline__ void cf_gemm_core(const __hip_bfloat16* __restrict__ Bl,
                                             const __hip_bfloat16* __restrict__ xs2,
                                             int wv, int il, int hi,
                                             f32acc (&acc)[4][4]) {
    int crow[4];
    #pragma unroll
    for (int m = 0; m < 4; ++m) crow[m] = (m * 16 + il) * 512;

    auto loadB = [&](bf16x8 (&bb)[4], int kt) {
        #pragma unroll
        for (int n = 0; n < 4; ++n)
            bb[n] = *(const bf16x8*)(xs2 + (size_t)((wv * 4 + n) * 64 + kt * 4 + hi) * 128 + il * 8);
    };
    auto step = [&](const bf16x8 (&bb)[4], int kt) {
        bf16x8 a[4];
        #pragma unroll
        for (int m = 0; m < 4; ++m) {
            const int c = m * 16 + il;
            const int q = (kt * 4 + hi) ^ (c & 7);
            a[m] = *(const bf16x8*)&Bl[crow[m] + q * 8];
        }
        #pragma unroll
        for (int m = 0; m < 4; ++m)
            #pragma unroll
            for (int n = 0; n < 4; ++n)
                acc[m][n] = __builtin_amdgcn_mfma_f32_16x16x32_bf16(a[m], bb[n], acc[m][n], 0, 0, 0);
    };

    bf16x8 b0[4], b1[4];
    loadB(b0, 0);
    #pragma unroll
    for (int kt = 0; kt < 16; kt += 2) {
        if (kt + 1 < 16) loadB(b1, kt + 1);
        step(b0, kt);
        if (kt + 2 < 16) loadB(b0, kt + 2);
        if (kt + 1 < 16) step(b1, kt + 1);
    }
}

// ------------- kernel 5a: GEMM from pre-built panel images (fast path) ----------
__global__ __launch_bounds__(512, 4) void cf_kgemm4(
    const __hip_bfloat16* __restrict__ xs2,
    const __hip_bfloat16* __restrict__ Wt,
    const int* __restrict__ label,
    const float* __restrict__ cosm,
    const float* __restrict__ finl,
    const float* __restrict__ tp,
    float* __restrict__ out) {
    __shared__ __attribute__((aligned(16))) __hip_bfloat16 Bl[64 * 512];

    const int tid  = threadIdx.x;
    const int wv   = tid >> 6;
    const int lane = tid & 63;
    const int il   = lane & 15;
    const int hi   = lane >> 4;
    const int cb   = blockIdx.x * BN;

    // linear contiguous 64KB copy of the pre-swizzled panel image
    {
        const __hip_bfloat16* src = Wt + (size_t)blockIdx.x * PANEL_ELEMS;
        bf16x8 r[8];
        #pragma unroll
        for (int i = 0; i < 8; ++i)
            r[i] = *(const bf16x8*)(src + i * 4096 + tid * 8);
        #pragma unroll
        for (int i = 0; i < 8; ++i)
            *(bf16x8*)&Bl[i * 4096 + tid * 8] = r[i];
    }
    __syncthreads();

    f32acc acc[4][4];
    #pragma unroll
    for (int m = 0; m < 4; ++m)
        #pragma unroll
        for (int n = 0; n < 4; ++n)
            acc[m][n] = (f32acc){0.f, 0.f, 0.f, 0.f};

    cf_gemm_core(Bl, xs2, wv, il, hi, acc);
    cf_epilogue(acc, wv, il, hi, cb, label, cosm, finl, tp[0], out);
}

// ------------- kernel 5b: GEMM staging W f32 directly (fallback path) -----------
__global__ __launch_bounds__(512, 4) void cf_kgemm(
    const __hip_bfloat16* __restrict__ xs2,
    const float* __restrict__ W,
    const int* __restrict__ label,
    const float* __restrict__ cosm,
    const float* __restrict__ finl,
    const float* __restrict__ tp,
    float* __restrict__ out) {
    __shared__ __attribute__((aligned(16))) __hip_bfloat16 Bl[64 * 512];

    const int tid  = threadIdx.x;
    const int wv   = tid >> 6;
    const int lane = tid & 63;
    const int il   = lane & 15;
    const int hi   = lane >> 4;
    const int cb   = blockIdx.x * BN;

    {
        const int c4 = (tid & 15) * 4;
        const int k8 = tid >> 4;
        const bool ok = (cb + c4) < C_DIM;
        #pragma unroll
        for (int kk2 = 0; kk2 < 2; ++kk2) {
            const int kb = kk2 * 256 + k8 * 8;
            f32x4 v[8];
            #pragma unroll
            for (int j = 0; j < 8; ++j) {
                if (ok) v[j] = *(const f32x4*)(W + (size_t)(kb + j) * C_DIM + cb + c4);
                else    v[j] = (f32x4){0.f, 0.f, 0.f, 0.f};
            }
            const int q = kk2 * 32 + k8;
            #pragma unroll
            for (int cc = 0; cc < 4; ++cc) {
                const int c = c4 + cc;
                union { __hip_bfloat16 h[8]; bf16x8 b; } p;
                #pragma unroll
                for (int j = 0; j < 8; ++j) p.h[j] = __float2bfloat16(v[j][cc]);
                *(bf16x8*)&Bl[c * 512 + (q ^ (c & 7)) * 8] = p.b;
            }
        }
    }
    __syncthreads();

    f32acc acc[4][4];
    #pragma unroll
    for (int m = 0; m < 4; ++m)
        #pragma unroll
        for (int n = 0; n < 4; ++n)
            acc[m][n] = (f32acc){0.f, 0.f, 0.f, 0.f};

    cf_gemm_core(Bl, xs2, wv, il, hi, acc);
    cf_epilogue(acc, wv, il, hi, cb, label, cosm, finl, tp[0], out);
}

extern "C" void kernel_launch(void* const* d_in, const int* in_sizes, int n_in,
                              void* d_out, int out_size, void* d_ws, size_t ws_size,
                              hipStream_t stream) {
    const float* x   = (const float*)d_in[0];
    const float* W   = (const float*)d_in[1];
    const int* label = (const int*)d_in[2];
    float* out = (float*)d_out;

    char* ws = (char*)d_ws;
    float* norm2 = (float*)ws;             // 512 f32 (sum of squares)
    float* tl  = norm2 + 512;
    float* cm  = tl + 512;
    float* fl  = cm + 512;
    float* tsc = fl + 512;
    __hip_bfloat16* xs2 = (__hip_bfloat16*)(ws + 16384);       // 512 KB
    __hip_bfloat16* Wt  = (__hip_bfloat16*)(ws + (1 << 20));   // ~97.7 MB

    const size_t need = (size_t)(1 << 20) + (size_t)NPANEL * PANEL_ELEMS * sizeof(__hip_bfloat16);
    const bool big = (ws_size >= need);

    if (big) {
        hipMemsetAsync(norm2, 0, 512 * sizeof(float), stream);
        cf_kprep<<<NSG * 16, 512, 0, stream>>>(W, norm2, Wt);
    } else {
        cf_knorm<<<DDIM, 256, 0, stream>>>(W, norm2);
    }
    cf_kxs2<<<128, 256, 0, stream>>>(x, norm2, xs2);
    cf_ktgt<<<NROW, 64, 0, stream>>>(x, W, norm2, label, tl, cm, fl);
    cf_kt<<<1, 512, 0, stream>>>(tl, tsc);

    if (big)
        cf_kgemm4<<<NPANEL, 512, 0, stream>>>(xs2, Wt, label, cm, fl, tsc, out);
    else
        cf_kgemm<<<NPANEL, 512, 0, stream>>>(xs2, W, label, cm, fl, tsc, out);
}